// Round 8
// baseline (405.580 us; speedup 1.0000x reference)
//
#include <hip/hip_runtime.h>
#include <hip/hip_bf16.h>
#include <cstdint>

#define TB 256
#define SCAN_T 256
#define SCAN_C 2048

__device__ __forceinline__ float lrelu_exp(float e){
  e = e > 0.0f ? e : 0.2f * e;
  return __expf(e);
}
__device__ __forceinline__ unsigned short f2bf(float f){
  unsigned u = __float_as_uint(f);
  u = (u + 0x7fffu + ((u >> 16) & 1u)) >> 16;   // RNE
  return (unsigned short)u;
}
__device__ __forceinline__ float bf2f(unsigned short s){
  return __uint_as_float(((unsigned)s) << 16);
}
__device__ __forceinline__ float lof(unsigned u){ return __uint_as_float(u << 16); }
__device__ __forceinline__ float hif(unsigned u){ return __uint_as_float(u & 0xffff0000u); }
__device__ __forceinline__ unsigned pack2(float a, float b){
  return (unsigned)f2bf(a) | ((unsigned)f2bf(b) << 16);
}

// ---------------- CSR build (dst-indexed) ----------------
__global__ __launch_bounds__(TB) void k_histrank(const int* __restrict__ ei, int E, int n,
                                                 int* __restrict__ deg, int* __restrict__ rank){
  int b0 = blockIdx.x * (TB * 8) + threadIdx.x;
  int d[8]; int r[8]; bool ok[8];
  #pragma unroll
  for (int u = 0; u < 8; ++u){
    int e = b0 + u * TB;
    ok[u] = (e < E);
    d[u] = ok[u] ? ei[E + e] : 0;
    ok[u] = ok[u] && ((unsigned)d[u] < (unsigned)n);
  }
  #pragma unroll
  for (int u = 0; u < 8; ++u)
    if (ok[u]) r[u] = atomicAdd(&deg[d[u]], 1);
  #pragma unroll
  for (int u = 0; u < 8; ++u)
    if (ok[u]) rank[b0 + u * TB] = r[u];
}

__global__ __launch_bounds__(SCAN_T) void k_scan1(const int* __restrict__ deg, int n,
                                                  int* __restrict__ excl, int* __restrict__ partials){
  __shared__ int sums[SCAN_T];
  int t = threadIdx.x;
  int base = blockIdx.x * SCAN_C + t * 8;
  int v[8]; int s = 0;
  #pragma unroll
  for (int i = 0; i < 8; ++i){ int idx = base + i; v[i] = (idx < n) ? deg[idx] : 0; s += v[i]; }
  sums[t] = s;
  __syncthreads();
  for (int off = 1; off < SCAN_T; off <<= 1){
    int add = (t >= off) ? sums[t - off] : 0;
    __syncthreads();
    sums[t] += add;
    __syncthreads();
  }
  int run = sums[t] - s;
  if (t == SCAN_T - 1) partials[blockIdx.x] = sums[t];
  #pragma unroll
  for (int i = 0; i < 8; ++i){ int idx = base + i; if (idx < n) excl[idx] = run; run += v[i]; }
}

__global__ void k_scan2(int* partials, int nb){
  int lane = threadIdx.x;
  int orig = (lane < nb) ? partials[lane] : 0;
  int v = orig;
  for (int off = 1; off < 64; off <<= 1){
    int u = __shfl_up(v, off);
    if (lane >= off) v += u;
  }
  if (lane < nb) partials[lane] = v - orig;
}

__global__ __launch_bounds__(TB) void k_scan3(int* __restrict__ excl, int n, const int* __restrict__ partials){
  int i = blockIdx.x * TB + threadIdx.x;
  if (i < n) excl[i] += partials[i / SCAN_C];
}

// scatter without atomics, non-temporal random store
__global__ __launch_bounds__(TB) void k_scatter(const int* __restrict__ ei, int E, int n,
                                                const int* __restrict__ excl, const int* __restrict__ rank,
                                                int* __restrict__ col){
  int b0 = blockIdx.x * (TB * 4) + threadIdx.x;
  #pragma unroll
  for (int u = 0; u < 4; ++u){
    int e = b0 + u * TB;
    if (e >= E) continue;
    int s = ei[e];
    int d = ei[E + e];
    if ((unsigned)d >= (unsigned)n || (unsigned)s >= (unsigned)n) continue;
    int pos = excl[d] + rank[e];
    __builtin_nontemporal_store(s, &col[pos]);
  }
}

// ---------------- GEMM1: h1b[N,128](bf16) = x[N,128] @ W1[128,128] ----------------
__global__ __launch_bounds__(256) void k_gemm1(const float* __restrict__ x, const float* __restrict__ W,
                                               unsigned short* __restrict__ hb, int n){
  __shared__ float xs[32][128];
  __shared__ float ws[32][128];
  int t = threadIdx.x;
  int ng = t & 15, cg = t >> 4;
  int node0 = blockIdx.x * 128;
  int nodeL = t >> 1, kh = t & 1;
  float acc[8][8];
  #pragma unroll
  for (int i = 0; i < 8; ++i)
    #pragma unroll
    for (int j = 0; j < 8; ++j) acc[i][j] = 0.0f;

  for (int kc = 0; kc < 4; ++kc){
    int k0 = kc * 32;
    __syncthreads();
    {
      int gn = node0 + nodeL;
      const float4* src = (const float4*)(x + (size_t)gn * 128 + k0 + kh * 16);
      #pragma unroll
      for (int u = 0; u < 4; ++u){
        float4 f = (gn < n) ? src[u] : make_float4(0.f, 0.f, 0.f, 0.f);
        int kk = kh * 16 + u * 4;
        xs[kk + 0][nodeL] = f.x; xs[kk + 1][nodeL] = f.y;
        xs[kk + 2][nodeL] = f.z; xs[kk + 3][nodeL] = f.w;
      }
      const float4* wsrc = (const float4*)(W + (size_t)k0 * 128);
      float4* wdst = (float4*)(&ws[0][0]);
      #pragma unroll
      for (int u = 0; u < 4; ++u) wdst[t + 256 * u] = wsrc[t + 256 * u];
    }
    __syncthreads();
    #pragma unroll 8
    for (int k = 0; k < 32; ++k){
      float xv[8];
      #pragma unroll
      for (int i = 0; i < 8; ++i) xv[i] = xs[k][ng + 16 * i];
      float4 w0 = *(const float4*)&ws[k][cg * 8];
      float4 w1 = *(const float4*)&ws[k][cg * 8 + 4];
      float wv[8] = {w0.x, w0.y, w0.z, w0.w, w1.x, w1.y, w1.z, w1.w};
      #pragma unroll
      for (int i = 0; i < 8; ++i)
        #pragma unroll
        for (int j = 0; j < 8; ++j) acc[i][j] = fmaf(xv[i], wv[j], acc[i][j]);
    }
  }
  #pragma unroll
  for (int i = 0; i < 8; ++i){
    int gn = node0 + ng + 16 * i;
    if (gn < n){
      uint4 o;
      o.x = pack2(acc[i][0], acc[i][1]);
      o.y = pack2(acc[i][2], acc[i][3]);
      o.z = pack2(acc[i][4], acc[i][5]);
      o.w = pack2(acc[i][6], acc[i][7]);
      *(uint4*)(hb + (size_t)gn * 128 + cg * 8) = o;
    }
  }
}

// ---------------- att1: a_s/a_d [N,8] from h1b ----------------
__global__ __launch_bounds__(TB) void k_att1(const unsigned short* __restrict__ hb, const float* __restrict__ asw,
                                             const float* __restrict__ adw,
                                             float* __restrict__ a_s, float* __restrict__ a_d, int n8){
  int idx = blockIdx.x * TB + threadIdx.x;   // node*8 + h
  if (idx >= n8) return;
  int h = idx & 7;
  uint4 lo4 = *(const uint4*)(hb + (size_t)idx * 16);
  uint4 hi4 = *(const uint4*)(hb + (size_t)idx * 16 + 8);
  float v[16];
  unsigned w_[8] = {lo4.x, lo4.y, lo4.z, lo4.w, hi4.x, hi4.y, hi4.z, hi4.w};
  #pragma unroll
  for (int u = 0; u < 8; ++u){
    v[2 * u]     = lof(w_[u]);
    v[2 * u + 1] = hif(w_[u]);
  }
  float ss = 0.f, dd = 0.f;
  #pragma unroll
  for (int u = 0; u < 16; ++u){
    ss = fmaf(v[u], asw[h * 16 + u], ss);
    dd = fmaf(v[u], adw[h * 16 + u], dd);
  }
  a_s[idx] = ss; a_d[idx] = dd;
}

// ---------------- agg1: fused weights, predicated 16-edge loop, 2 edge-groups ----------------
__global__ __launch_bounds__(256) void k_agg1(const unsigned short* __restrict__ hb, const float* __restrict__ a_s,
    const float* __restrict__ a_d, const int* __restrict__ col,
    const int* __restrict__ excl, const int* __restrict__ deg,
    const float* __restrict__ b1, unsigned short* __restrict__ out1b, int n){
  int tl = threadIdx.x & 63;
  int node = blockIdx.x * 4 + (threadIdx.x >> 6);
  if (node >= n) return;
  int g  = tl >> 5;          // edge group 0/1
  int il = tl & 31;          // channels [4il, 4il+4)
  int h  = il >> 2;
  float adn = a_d[(size_t)node * 8 + h];        // loop-invariant: dst == node
  float acc0 = 0.f, acc1 = 0.f, acc2 = 0.f, acc3 = 0.f, denom = 0.f;
  if (g == 0){
    float wSelf = lrelu_exp(a_s[(size_t)node * 8 + h] + adn);
    uint2 hv = *(const uint2*)(hb + (size_t)node * 128 + il * 4);
    acc0 = wSelf * lof(hv.x); acc1 = wSelf * hif(hv.x);
    acc2 = wSelf * lof(hv.y); acc3 = wSelf * hif(hv.y);
    denom = wSelf;
  }
  int start = excl[node];
  int end = start + deg[node];
  for (int pp = start; pp < end; pp += 16){
    int s[8]; float as[8]; uint2 v[8]; bool ok[8];
    #pragma unroll
    for (int u = 0; u < 8; ++u){
      int e = pp + 2 * u + g;
      ok[u] = e < end;
      s[u] = col[ok[u] ? e : (end - 1)];
    }
    #pragma unroll
    for (int u = 0; u < 8; ++u) as[u] = a_s[(size_t)s[u] * 8 + h];
    #pragma unroll
    for (int u = 0; u < 8; ++u) v[u] = *(const uint2*)(hb + (size_t)s[u] * 128 + il * 4);
    #pragma unroll
    for (int u = 0; u < 8; ++u){
      float w = ok[u] ? lrelu_exp(as[u] + adn) : 0.0f;
      acc0 = fmaf(w, lof(v[u].x), acc0);
      acc1 = fmaf(w, hif(v[u].x), acc1);
      acc2 = fmaf(w, lof(v[u].y), acc2);
      acc3 = fmaf(w, hif(v[u].y), acc3);
      denom += w;
    }
  }
  acc0 += __shfl_xor(acc0, 32); acc1 += __shfl_xor(acc1, 32);
  acc2 += __shfl_xor(acc2, 32); acc3 += __shfl_xor(acc3, 32);
  denom += __shfl_xor(denom, 32);
  float inv = 1.0f / denom;
  float4 bb = *(const float4*)(b1 + il * 4);
  float o0 = fmaf(acc0, inv, bb.x); o0 = o0 > 0.f ? o0 : 0.f;
  float o1 = fmaf(acc1, inv, bb.y); o1 = o1 > 0.f ? o1 : 0.f;
  float o2 = fmaf(acc2, inv, bb.z); o2 = o2 > 0.f ? o2 : 0.f;
  float o3 = fmaf(acc3, inv, bb.w); o3 = o3 > 0.f ? o3 : 0.f;
  if (g == 0){
    uint2 o; o.x = pack2(o0, o1); o.y = pack2(o2, o3);
    *(uint2*)(out1b + (size_t)node * 128 + il * 4) = o;
  }
}

// ---------------- GEMM2: h2b[N,64-padded](bf16) = out1b[N,128](bf16) @ W2[128,40] ----------------
__global__ __launch_bounds__(256) void k_gemm2(const unsigned short* __restrict__ ab, const float* __restrict__ W2,
                                               unsigned short* __restrict__ h2b, int n){
  __shared__ float xs[32][256];
  __shared__ float ws[128][40];
  int t = threadIdx.x;
  for (int i = t; i < 128 * 40; i += 256) (&ws[0][0])[i] = W2[i];
  int ng = t & 63, cg = t >> 6;
  int node0 = blockIdx.x * 256;
  float acc[4][10];
  #pragma unroll
  for (int i = 0; i < 4; ++i)
    #pragma unroll
    for (int j = 0; j < 10; ++j) acc[i][j] = 0.0f;

  for (int kc = 0; kc < 4; ++kc){
    int k0 = kc * 32;
    __syncthreads();
    {
      int gn = node0 + t;
      uint4 q[2];
      if (gn < n){
        const uint4* src = (const uint4*)(ab + (size_t)gn * 128 + k0);
        q[0] = src[0]; q[1] = src[1];
      } else {
        q[0] = make_uint4(0,0,0,0); q[1] = make_uint4(0,0,0,0);
      }
      #pragma unroll
      for (int u = 0; u < 2; ++u){
        unsigned w4[4] = {q[u].x, q[u].y, q[u].z, q[u].w};
        #pragma unroll
        for (int j = 0; j < 4; ++j){
          int kk = u * 8 + j * 2;
          xs[kk][t]     = lof(w4[j]);
          xs[kk + 1][t] = hif(w4[j]);
        }
      }
      uint4 r[2];
      if (gn < n){
        const uint4* src = (const uint4*)(ab + (size_t)gn * 128 + k0 + 16);
        r[0] = src[0]; r[1] = src[1];
      } else {
        r[0] = make_uint4(0,0,0,0); r[1] = make_uint4(0,0,0,0);
      }
      #pragma unroll
      for (int u = 0; u < 2; ++u){
        unsigned w4[4] = {r[u].x, r[u].y, r[u].z, r[u].w};
        #pragma unroll
        for (int j = 0; j < 4; ++j){
          int kk = 16 + u * 8 + j * 2;
          xs[kk][t]     = lof(w4[j]);
          xs[kk + 1][t] = hif(w4[j]);
        }
      }
    }
    __syncthreads();
    #pragma unroll 4
    for (int k = 0; k < 32; ++k){
      float xv[4];
      #pragma unroll
      for (int i = 0; i < 4; ++i) xv[i] = xs[k][ng + 64 * i];
      float wv[10];
      #pragma unroll
      for (int j = 0; j < 10; ++j) wv[j] = ws[k0 + k][cg * 10 + j];
      #pragma unroll
      for (int i = 0; i < 4; ++i)
        #pragma unroll
        for (int j = 0; j < 10; ++j) acc[i][j] = fmaf(xv[i], wv[j], acc[i][j]);
    }
  }
  #pragma unroll
  for (int i = 0; i < 4; ++i){
    int gn = node0 + ng + 64 * i;
    if (gn < n){
      unsigned pk[5];
      #pragma unroll
      for (int j = 0; j < 5; ++j) pk[j] = pack2(acc[i][2 * j], acc[i][2 * j + 1]);
      unsigned* dst = (unsigned*)h2b + (size_t)gn * 32 + cg * 5;   // padded stride 64 ushorts
      #pragma unroll
      for (int j = 0; j < 5; ++j) dst[j] = pk[j];
    }
  }
}

// ---------------- att2: a_s/a_d [N] from h2b (stride 64) ----------------
__global__ __launch_bounds__(TB) void k_att2(const unsigned short* __restrict__ h2b, const float* __restrict__ asw,
                                             const float* __restrict__ adw,
                                             float* __restrict__ a_s, float* __restrict__ a_d, int n){
  int t = threadIdx.x;
  int node = blockIdx.x * 32 + (t >> 3);
  int sub = t & 7;
  if (node >= n) return;
  float ss = 0.f, dd = 0.f;
  for (int j = sub; j < 40; j += 8){
    float v = bf2f(h2b[(size_t)node * 64 + j]);
    ss = fmaf(v, asw[j], ss);
    dd = fmaf(v, adw[j], dd);
  }
  #pragma unroll
  for (int off = 1; off < 8; off <<= 1){
    ss += __shfl_xor(ss, off);
    dd += __shfl_xor(dd, off);
  }
  if (sub == 0){ a_s[node] = ss; a_d[node] = dd; }
}

// ---------------- agg2 + log_softmax: fused weights, predicated loop ----------------
__global__ __launch_bounds__(256) void k_agg2(const unsigned short* __restrict__ h2b, const float* __restrict__ a_s,
    const float* __restrict__ a_d, const int* __restrict__ col,
    const int* __restrict__ excl, const int* __restrict__ deg,
    const float* __restrict__ b2, float* __restrict__ out, int n){
  int tl = threadIdx.x & 63;
  int node = blockIdx.x * 4 + (threadIdx.x >> 6);
  if (node >= n) return;
  int g = tl >> 5, il = tl & 31;
  bool act = il < 20;                       // channels 2il, 2il+1 (< 40)
  const unsigned* h2u = (const unsigned*)h2b;   // rows of 32 uints (64 ushorts, padded)
  float adn = a_d[node];                    // loop-invariant: dst == node
  float acc0 = 0.f, acc1 = 0.f, denom = 0.f;
  if (g == 0){
    float wSelf = lrelu_exp(a_s[node] + adn);
    unsigned hv = h2u[(size_t)node * 32 + il];
    acc0 = wSelf * lof(hv); acc1 = wSelf * hif(hv);
    denom = wSelf;
  }
  int start = excl[node];
  int end = start + deg[node];
  for (int pp = start; pp < end; pp += 16){
    int s[8]; float as[8]; unsigned v[8]; bool ok[8];
    #pragma unroll
    for (int u = 0; u < 8; ++u){
      int e = pp + 2 * u + g;
      ok[u] = e < end;
      s[u] = col[ok[u] ? e : (end - 1)];
    }
    #pragma unroll
    for (int u = 0; u < 8; ++u) as[u] = a_s[s[u]];
    #pragma unroll
    for (int u = 0; u < 8; ++u) v[u] = h2u[(size_t)s[u] * 32 + il];
    #pragma unroll
    for (int u = 0; u < 8; ++u){
      float w = ok[u] ? lrelu_exp(as[u] + adn) : 0.0f;
      acc0 = fmaf(w, lof(v[u]), acc0);
      acc1 = fmaf(w, hif(v[u]), acc1);
      denom += w;
    }
  }
  acc0 += __shfl_xor(acc0, 32);
  acc1 += __shfl_xor(acc1, 32);
  denom += __shfl_xor(denom, 32);
  float inv = 1.0f / denom;
  float2 bb = act ? *(const float2*)(b2 + il * 2) : make_float2(0.f, 0.f);
  float vv0 = act ? fmaf(acc0, inv, bb.x) : -1e30f;
  float vv1 = act ? fmaf(acc1, inv, bb.y) : -1e30f;
  float m = fmaxf(vv0, vv1);
  #pragma unroll
  for (int off = 16; off >= 1; off >>= 1) m = fmaxf(m, __shfl_xor(m, off));
  float S = act ? (__expf(vv0 - m) + __expf(vv1 - m)) : 0.f;
  #pragma unroll
  for (int off = 16; off >= 1; off >>= 1) S += __shfl_xor(S, off);
  float ls = __logf(S);
  if (tl < 20){
    float2 o = make_float2(vv0 - m - ls, vv1 - m - ls);
    *(float2*)(out + (size_t)node * 40 + il * 2) = o;
  }
}

extern "C" void kernel_launch(void* const* d_in, const int* in_sizes, int n_in,
                              void* d_out, int out_size, void* d_ws, size_t ws_size,
                              hipStream_t stream){
  const float* x    = (const float*)d_in[0];
  const int*   ei   = (const int*)d_in[1];          // int32 (jax x64 disabled)
  const float* W1   = (const float*)d_in[2];
  const float* as1w = (const float*)d_in[3];
  const float* ad1w = (const float*)d_in[4];
  const float* b1   = (const float*)d_in[5];
  const float* W2   = (const float*)d_in[6];
  const float* as2w = (const float*)d_in[7];
  const float* ad2w = (const float*)d_in[8];
  const float* b2   = (const float*)d_in[9];
  float* out = (float*)d_out;
  const int N = in_sizes[0] / 128;
  const int E = in_sizes[1] / 2;

  char* p = (char*)d_ws;
  auto alloc = [&](size_t bytes) -> void* {
    void* r = (void*)p;
    p += (bytes + 511) & ~(size_t)511;
    return r;
  };
  int*            deg      = (int*)           alloc((size_t)N * 4);
  int*            excl     = (int*)           alloc((size_t)N * 4);
  int*            partials = (int*)           alloc(64 * 4);
  int*            rank     = (int*)           alloc((size_t)E * 4);
  int*            col      = (int*)           alloc((size_t)E * 4);
  float*          a_s1     = (float*)         alloc((size_t)N * 8 * 4);
  float*          a_d1     = (float*)         alloc((size_t)N * 8 * 4);
  unsigned short* out1b    = (unsigned short*)alloc((size_t)N * 128 * 2);
  unsigned short* h1b      = (unsigned short*)alloc((size_t)N * 128 * 2);
  // layer-2 temporaries overlay h1b (dead after agg1): h2b = N*64 ushorts (padded)
  unsigned short* h2b  = h1b;
  float*          a_s2 = (float*)((char*)h1b + (size_t)N * 128);  // right after padded h2b
  float*          a_d2 = a_s2 + N;

  hipMemsetAsync(deg, 0, (size_t)N * 4, stream);

  int gE8 = (E + TB * 8 - 1) / (TB * 8);
  int gE4 = (E + TB * 4 - 1) / (TB * 4);
  int nchunk = (N + SCAN_C - 1) / SCAN_C;

  k_histrank<<<gE8, TB, 0, stream>>>(ei, E, N, deg, rank);
  k_scan1   <<<nchunk, SCAN_T, 0, stream>>>(deg, N, excl, partials);
  k_scan2   <<<1, 64, 0, stream>>>(partials, nchunk);
  k_scan3   <<<(N + TB - 1) / TB, TB, 0, stream>>>(excl, N, partials);
  k_scatter <<<gE4, TB, 0, stream>>>(ei, E, N, excl, rank, col);

  k_gemm1   <<<(N + 127) / 128, 256, 0, stream>>>(x, W1, h1b, N);
  k_att1    <<<(N * 8 + TB - 1) / TB, TB, 0, stream>>>(h1b, as1w, ad1w, a_s1, a_d1, N * 8);
  k_agg1    <<<(N + 3) / 4, 256, 0, stream>>>(h1b, a_s1, a_d1, col, excl, deg, b1, out1b, N);

  k_gemm2   <<<(N + 255) / 256, 256, 0, stream>>>(out1b, W2, h2b, N);
  k_att2    <<<(N + 31) / 32, TB, 0, stream>>>(h2b, as2w, ad2w, a_s2, a_d2, N);
  k_agg2    <<<(N + 3) / 4, 256, 0, stream>>>(h2b, a_s2, a_d2, col, excl, deg, b2, out, N);
}

// Round 9
// 390.526 us; speedup vs baseline: 1.0385x; 1.0385x over previous
//
#include <hip/hip_runtime.h>
#include <hip/hip_bf16.h>
#include <cstdint>

#define TB 256
#define SCAN_T 256
#define SCAN_C 2048

typedef __attribute__((ext_vector_type(8))) short bf16x8;
typedef __attribute__((ext_vector_type(4))) float f32x4;

__device__ __forceinline__ float lrelu_exp(float e){
  e = e > 0.0f ? e : 0.2f * e;
  return __expf(e);
}
__device__ __forceinline__ unsigned short f2bf(float f){
  unsigned u = __float_as_uint(f);
  u = (u + 0x7fffu + ((u >> 16) & 1u)) >> 16;   // RNE
  return (unsigned short)u;
}
__device__ __forceinline__ float bf2f(unsigned short s){
  return __uint_as_float(((unsigned)s) << 16);
}
__device__ __forceinline__ float lof(unsigned u){ return __uint_as_float(u << 16); }
__device__ __forceinline__ float hif(unsigned u){ return __uint_as_float(u & 0xffff0000u); }
__device__ __forceinline__ unsigned pack2(float a, float b){
  return (unsigned)f2bf(a) | ((unsigned)f2bf(b) << 16);
}

// ---------------- CSR build (dst-indexed) ----------------
__global__ __launch_bounds__(TB) void k_histrank(const int* __restrict__ ei, int E, int n,
                                                 int* __restrict__ deg, int* __restrict__ rank){
  int b0 = blockIdx.x * (TB * 8) + threadIdx.x;
  int d[8]; int r[8]; bool ok[8];
  #pragma unroll
  for (int u = 0; u < 8; ++u){
    int e = b0 + u * TB;
    ok[u] = (e < E);
    d[u] = ok[u] ? ei[E + e] : 0;
    ok[u] = ok[u] && ((unsigned)d[u] < (unsigned)n);
  }
  #pragma unroll
  for (int u = 0; u < 8; ++u)
    if (ok[u]) r[u] = atomicAdd(&deg[d[u]], 1);
  #pragma unroll
  for (int u = 0; u < 8; ++u)
    if (ok[u]) rank[b0 + u * TB] = r[u];
}

__global__ __launch_bounds__(SCAN_T) void k_scan1(const int* __restrict__ deg, int n,
                                                  int* __restrict__ excl, int* __restrict__ partials){
  __shared__ int sums[SCAN_T];
  int t = threadIdx.x;
  int base = blockIdx.x * SCAN_C + t * 8;
  int v[8]; int s = 0;
  #pragma unroll
  for (int i = 0; i < 8; ++i){ int idx = base + i; v[i] = (idx < n) ? deg[idx] : 0; s += v[i]; }
  sums[t] = s;
  __syncthreads();
  for (int off = 1; off < SCAN_T; off <<= 1){
    int add = (t >= off) ? sums[t - off] : 0;
    __syncthreads();
    sums[t] += add;
    __syncthreads();
  }
  int run = sums[t] - s;
  if (t == SCAN_T - 1) partials[blockIdx.x] = sums[t];
  #pragma unroll
  for (int i = 0; i < 8; ++i){ int idx = base + i; if (idx < n) excl[idx] = run; run += v[i]; }
}

__global__ void k_scan2(int* partials, int nb){
  int lane = threadIdx.x;
  int orig = (lane < nb) ? partials[lane] : 0;
  int v = orig;
  for (int off = 1; off < 64; off <<= 1){
    int u = __shfl_up(v, off);
    if (lane >= off) v += u;
  }
  if (lane < nb) partials[lane] = v - orig;
}

__global__ __launch_bounds__(TB) void k_scan3(int* __restrict__ excl, int n, const int* __restrict__ partials){
  int i = blockIdx.x * TB + threadIdx.x;
  if (i < n) excl[i] += partials[i / SCAN_C];
}

// scatter without atomics, non-temporal random store
__global__ __launch_bounds__(TB) void k_scatter(const int* __restrict__ ei, int E, int n,
                                                const int* __restrict__ excl, const int* __restrict__ rank,
                                                int* __restrict__ col){
  int b0 = blockIdx.x * (TB * 4) + threadIdx.x;
  #pragma unroll
  for (int u = 0; u < 4; ++u){
    int e = b0 + u * TB;
    if (e >= E) continue;
    int s = ei[e];
    int d = ei[E + e];
    if ((unsigned)d >= (unsigned)n || (unsigned)s >= (unsigned)n) continue;
    int pos = excl[d] + rank[e];
    __builtin_nontemporal_store(s, &col[pos]);
  }
}

// ---------------- W1 transpose+pack: W1t[c][k] (bf16) ----------------
__global__ __launch_bounds__(256) void k_w1t(const float* __restrict__ W, unsigned short* __restrict__ Wt){
  int i = blockIdx.x * 256 + threadIdx.x;
  if (i >= 128 * 128) return;
  int k = i >> 7, c = i & 127;
  Wt[c * 128 + k] = f2bf(W[i]);
}

// ---------------- GEMM1 (MFMA bf16): h1b[N,128] = x[N,128] @ W1[128,128] ----------------
__global__ __launch_bounds__(256) void k_gemm1(const float* __restrict__ x, const unsigned short* __restrict__ Wt,
                                               unsigned short* __restrict__ hb, int n){
  __shared__ unsigned short As[128][40];    // x chunk, +8 pad
  __shared__ unsigned short Bs[128][136];   // full W1t [col][k], +8 pad
  int t = threadIdx.x;
  int l = t & 63, wid = t >> 6;
  int wm = wid >> 1, wn = wid & 1;
  int node0 = blockIdx.x * 128;
  {
    int c = t >> 1, seg = t & 1;
    #pragma unroll
    for (int u = 0; u < 8; ++u)
      *(uint4*)&Bs[c][seg * 64 + u * 8] = *(const uint4*)&Wt[c * 128 + seg * 64 + u * 8];
  }
  f32x4 acc[4][4];
  #pragma unroll
  for (int i = 0; i < 4; ++i)
    #pragma unroll
    for (int j = 0; j < 4; ++j) acc[i][j] = (f32x4){0.f, 0.f, 0.f, 0.f};

  int lrow = l & 15, lk8 = (l >> 4) * 8;
  for (int kc = 0; kc < 4; ++kc){
    __syncthreads();
    {
      int row = t >> 1, kh = t & 1;
      int gn = node0 + row;
      const float4* src = (const float4*)(x + (size_t)gn * 128 + kc * 32 + kh * 16);
      float4 z = make_float4(0.f, 0.f, 0.f, 0.f);
      float4 f0 = (gn < n) ? src[0] : z;
      float4 f1 = (gn < n) ? src[1] : z;
      float4 f2 = (gn < n) ? src[2] : z;
      float4 f3 = (gn < n) ? src[3] : z;
      uint4 p0, p1;
      p0.x = pack2(f0.x, f0.y); p0.y = pack2(f0.z, f0.w);
      p0.z = pack2(f1.x, f1.y); p0.w = pack2(f1.z, f1.w);
      p1.x = pack2(f2.x, f2.y); p1.y = pack2(f2.z, f2.w);
      p1.z = pack2(f3.x, f3.y); p1.w = pack2(f3.z, f3.w);
      *(uint4*)&As[row][kh * 16]     = p0;
      *(uint4*)&As[row][kh * 16 + 8] = p1;
    }
    __syncthreads();
    bf16x8 a[4], b[4];
    #pragma unroll
    for (int mi = 0; mi < 4; ++mi)
      a[mi] = *(const bf16x8*)&As[wm * 64 + mi * 16 + lrow][lk8];
    #pragma unroll
    for (int ni = 0; ni < 4; ++ni)
      b[ni] = *(const bf16x8*)&Bs[wn * 64 + ni * 16 + lrow][kc * 32 + lk8];
    #pragma unroll
    for (int mi = 0; mi < 4; ++mi)
      #pragma unroll
      for (int ni = 0; ni < 4; ++ni)
        acc[mi][ni] = __builtin_amdgcn_mfma_f32_16x16x32_bf16(a[mi], b[ni], acc[mi][ni], 0, 0, 0);
  }
  int rg = (l >> 4) * 4;
  #pragma unroll
  for (int mi = 0; mi < 4; ++mi){
    #pragma unroll
    for (int j = 0; j < 4; ++j){
      int gn = node0 + wm * 64 + mi * 16 + rg + j;
      if (gn < n){
        #pragma unroll
        for (int ni = 0; ni < 4; ++ni)
          hb[(size_t)gn * 128 + wn * 64 + ni * 16 + lrow] = f2bf(acc[mi][ni][j]);
      }
    }
  }
}

// ---------------- att1: a_s/a_d [N,8] from h1b ----------------
__global__ __launch_bounds__(TB) void k_att1(const unsigned short* __restrict__ hb, const float* __restrict__ asw,
                                             const float* __restrict__ adw,
                                             float* __restrict__ a_s, float* __restrict__ a_d, int n8){
  int idx = blockIdx.x * TB + threadIdx.x;   // node*8 + h
  if (idx >= n8) return;
  int h = idx & 7;
  uint4 lo4 = *(const uint4*)(hb + (size_t)idx * 16);
  uint4 hi4 = *(const uint4*)(hb + (size_t)idx * 16 + 8);
  float v[16];
  unsigned w_[8] = {lo4.x, lo4.y, lo4.z, lo4.w, hi4.x, hi4.y, hi4.z, hi4.w};
  #pragma unroll
  for (int u = 0; u < 8; ++u){
    v[2 * u]     = lof(w_[u]);
    v[2 * u + 1] = hif(w_[u]);
  }
  float ss = 0.f, dd = 0.f;
  #pragma unroll
  for (int u = 0; u < 16; ++u){
    ss = fmaf(v[u], asw[h * 16 + u], ss);
    dd = fmaf(v[u], adw[h * 16 + u], dd);
  }
  a_s[idx] = ss; a_d[idx] = dd;
}

// ---------------- agg1: fused weights, 2 edge-groups of 32 lanes (uint2 = 4 ch/lane) ----------------
__global__ __launch_bounds__(256) void k_agg1(const unsigned short* __restrict__ hb, const float* __restrict__ a_s,
    const float* __restrict__ a_d, const int* __restrict__ col,
    const int* __restrict__ excl, const int* __restrict__ deg,
    const float* __restrict__ b1, unsigned short* __restrict__ out1b, int n){
  int tl = threadIdx.x & 63;
  int node = blockIdx.x * 4 + (threadIdx.x >> 6);
  if (node >= n) return;
  int g  = tl >> 5;          // edge group 0/1
  int il = tl & 31;          // channels [4il, 4il+4)
  int h  = il >> 2;
  float adn = a_d[(size_t)node * 8 + h];        // loop-invariant: dst == node
  float acc0 = 0.f, acc1 = 0.f, acc2 = 0.f, acc3 = 0.f, denom = 0.f;
  if (g == 0){
    float wSelf = lrelu_exp(a_s[(size_t)node * 8 + h] + adn);
    uint2 hv = *(const uint2*)(hb + (size_t)node * 128 + il * 4);
    acc0 = wSelf * lof(hv.x); acc1 = wSelf * hif(hv.x);
    acc2 = wSelf * lof(hv.y); acc3 = wSelf * hif(hv.y);
    denom = wSelf;
  }
  int pp = excl[node];
  int end = pp + deg[node];
  for (; pp + 16 <= end; pp += 16){
    int s[8]; float as[8]; uint2 v[8];
    #pragma unroll
    for (int u = 0; u < 8; ++u) s[u] = col[pp + 2 * u + g];
    #pragma unroll
    for (int u = 0; u < 8; ++u) as[u] = a_s[(size_t)s[u] * 8 + h];
    #pragma unroll
    for (int u = 0; u < 8; ++u) v[u] = *(const uint2*)(hb + (size_t)s[u] * 128 + il * 4);
    #pragma unroll
    for (int u = 0; u < 8; ++u){
      float w = lrelu_exp(as[u] + adn);
      acc0 = fmaf(w, lof(v[u].x), acc0);
      acc1 = fmaf(w, hif(v[u].x), acc1);
      acc2 = fmaf(w, lof(v[u].y), acc2);
      acc3 = fmaf(w, hif(v[u].y), acc3);
      denom += w;
    }
  }
  for (; pp + 2 <= end; pp += 2){
    int e = pp + g;
    int s0 = col[e];
    float w = lrelu_exp(a_s[(size_t)s0 * 8 + h] + adn);
    uint2 v0 = *(const uint2*)(hb + (size_t)s0 * 128 + il * 4);
    acc0 = fmaf(w, lof(v0.x), acc0);
    acc1 = fmaf(w, hif(v0.x), acc1);
    acc2 = fmaf(w, lof(v0.y), acc2);
    acc3 = fmaf(w, hif(v0.y), acc3);
    denom += w;
  }
  if (pp < end && g == 0){
    int s0 = col[pp];
    float w = lrelu_exp(a_s[(size_t)s0 * 8 + h] + adn);
    uint2 v0 = *(const uint2*)(hb + (size_t)s0 * 128 + il * 4);
    acc0 = fmaf(w, lof(v0.x), acc0);
    acc1 = fmaf(w, hif(v0.x), acc1);
    acc2 = fmaf(w, lof(v0.y), acc2);
    acc3 = fmaf(w, hif(v0.y), acc3);
    denom += w;
  }
  acc0 += __shfl_xor(acc0, 32); acc1 += __shfl_xor(acc1, 32);
  acc2 += __shfl_xor(acc2, 32); acc3 += __shfl_xor(acc3, 32);
  denom += __shfl_xor(denom, 32);
  float inv = 1.0f / denom;
  float4 bb = *(const float4*)(b1 + il * 4);
  float o0 = fmaf(acc0, inv, bb.x); o0 = o0 > 0.f ? o0 : 0.f;
  float o1 = fmaf(acc1, inv, bb.y); o1 = o1 > 0.f ? o1 : 0.f;
  float o2 = fmaf(acc2, inv, bb.z); o2 = o2 > 0.f ? o2 : 0.f;
  float o3 = fmaf(acc3, inv, bb.w); o3 = o3 > 0.f ? o3 : 0.f;
  if (g == 0){
    uint2 o; o.x = pack2(o0, o1); o.y = pack2(o2, o3);
    *(uint2*)(out1b + (size_t)node * 128 + il * 4) = o;
  }
}

// ---------------- GEMM2: h2b[N,64-padded](bf16) = out1b[N,128](bf16) @ W2[128,40] ----------------
__global__ __launch_bounds__(256) void k_gemm2(const unsigned short* __restrict__ ab, const float* __restrict__ W2,
                                               unsigned short* __restrict__ h2b, int n){
  __shared__ float xs[32][256];
  __shared__ float ws[128][40];
  int t = threadIdx.x;
  for (int i = t; i < 128 * 40; i += 256) (&ws[0][0])[i] = W2[i];
  int ng = t & 63, cg = t >> 6;
  int node0 = blockIdx.x * 256;
  float acc[4][10];
  #pragma unroll
  for (int i = 0; i < 4; ++i)
    #pragma unroll
    for (int j = 0; j < 10; ++j) acc[i][j] = 0.0f;

  for (int kc = 0; kc < 4; ++kc){
    int k0 = kc * 32;
    __syncthreads();
    {
      int gn = node0 + t;
      uint4 q[2];
      if (gn < n){
        const uint4* src = (const uint4*)(ab + (size_t)gn * 128 + k0);
        q[0] = src[0]; q[1] = src[1];
      } else {
        q[0] = make_uint4(0,0,0,0); q[1] = make_uint4(0,0,0,0);
      }
      #pragma unroll
      for (int u = 0; u < 2; ++u){
        unsigned w4[4] = {q[u].x, q[u].y, q[u].z, q[u].w};
        #pragma unroll
        for (int j = 0; j < 4; ++j){
          int kk = u * 8 + j * 2;
          xs[kk][t]     = lof(w4[j]);
          xs[kk + 1][t] = hif(w4[j]);
        }
      }
      uint4 r[2];
      if (gn < n){
        const uint4* src = (const uint4*)(ab + (size_t)gn * 128 + k0 + 16);
        r[0] = src[0]; r[1] = src[1];
      } else {
        r[0] = make_uint4(0,0,0,0); r[1] = make_uint4(0,0,0,0);
      }
      #pragma unroll
      for (int u = 0; u < 2; ++u){
        unsigned w4[4] = {r[u].x, r[u].y, r[u].z, r[u].w};
        #pragma unroll
        for (int j = 0; j < 4; ++j){
          int kk = 16 + u * 8 + j * 2;
          xs[kk][t]     = lof(w4[j]);
          xs[kk + 1][t] = hif(w4[j]);
        }
      }
    }
    __syncthreads();
    #pragma unroll 4
    for (int k = 0; k < 32; ++k){
      float xv[4];
      #pragma unroll
      for (int i = 0; i < 4; ++i) xv[i] = xs[k][ng + 64 * i];
      float wv[10];
      #pragma unroll
      for (int j = 0; j < 10; ++j) wv[j] = ws[k0 + k][cg * 10 + j];
      #pragma unroll
      for (int i = 0; i < 4; ++i)
        #pragma unroll
        for (int j = 0; j < 10; ++j) acc[i][j] = fmaf(xv[i], wv[j], acc[i][j]);
    }
  }
  #pragma unroll
  for (int i = 0; i < 4; ++i){
    int gn = node0 + ng + 64 * i;
    if (gn < n){
      unsigned pk[5];
      #pragma unroll
      for (int j = 0; j < 5; ++j) pk[j] = pack2(acc[i][2 * j], acc[i][2 * j + 1]);
      unsigned* dst = (unsigned*)h2b + (size_t)gn * 32 + cg * 5;   // padded stride 64 ushorts
      #pragma unroll
      for (int j = 0; j < 5; ++j) dst[j] = pk[j];
    }
  }
}

// ---------------- att2: a_s/a_d [N] from h2b (stride 64) ----------------
__global__ __launch_bounds__(TB) void k_att2(const unsigned short* __restrict__ h2b, const float* __restrict__ asw,
                                             const float* __restrict__ adw,
                                             float* __restrict__ a_s, float* __restrict__ a_d, int n){
  int t = threadIdx.x;
  int node = blockIdx.x * 32 + (t >> 3);
  int sub = t & 7;
  if (node >= n) return;
  float ss = 0.f, dd = 0.f;
  for (int j = sub; j < 40; j += 8){
    float v = bf2f(h2b[(size_t)node * 64 + j]);
    ss = fmaf(v, asw[j], ss);
    dd = fmaf(v, adw[j], dd);
  }
  #pragma unroll
  for (int off = 1; off < 8; off <<= 1){
    ss += __shfl_xor(ss, off);
    dd += __shfl_xor(dd, off);
  }
  if (sub == 0){ a_s[node] = ss; a_d[node] = dd; }
}

// ---------------- agg2 + log_softmax: fused weights, 2 edge-groups (uint = 2 ch/lane) ----------------
__global__ __launch_bounds__(256) void k_agg2(const unsigned short* __restrict__ h2b, const float* __restrict__ a_s,
    const float* __restrict__ a_d, const int* __restrict__ col,
    const int* __restrict__ excl, const int* __restrict__ deg,
    const float* __restrict__ b2, float* __restrict__ out, int n){
  int tl = threadIdx.x & 63;
  int node = blockIdx.x * 4 + (threadIdx.x >> 6);
  if (node >= n) return;
  int g = tl >> 5, il = tl & 31;
  bool act = il < 20;                       // channels 2il, 2il+1 (< 40)
  const unsigned* h2u = (const unsigned*)h2b;   // rows of 32 uints (64 ushorts, padded)
  float adn = a_d[node];                    // loop-invariant: dst == node
  float acc0 = 0.f, acc1 = 0.f, denom = 0.f;
  if (g == 0){
    float wSelf = lrelu_exp(a_s[node] + adn);
    unsigned hv = h2u[(size_t)node * 32 + il];
    acc0 = wSelf * lof(hv); acc1 = wSelf * hif(hv);
    denom = wSelf;
  }
  int pp = excl[node];
  int end = pp + deg[node];
  for (; pp + 16 <= end; pp += 16){
    int s[8]; float as[8]; unsigned v[8];
    #pragma unroll
    for (int u = 0; u < 8; ++u) s[u] = col[pp + 2 * u + g];
    #pragma unroll
    for (int u = 0; u < 8; ++u) as[u] = a_s[s[u]];
    #pragma unroll
    for (int u = 0; u < 8; ++u) v[u] = h2u[(size_t)s[u] * 32 + il];
    #pragma unroll
    for (int u = 0; u < 8; ++u){
      float w = lrelu_exp(as[u] + adn);
      acc0 = fmaf(w, lof(v[u]), acc0);
      acc1 = fmaf(w, hif(v[u]), acc1);
      denom += w;
    }
  }
  for (; pp + 2 <= end; pp += 2){
    int e = pp + g;
    int s0 = col[e];
    float w = lrelu_exp(a_s[s0] + adn);
    unsigned v0 = h2u[(size_t)s0 * 32 + il];
    acc0 = fmaf(w, lof(v0), acc0);
    acc1 = fmaf(w, hif(v0), acc1);
    denom += w;
  }
  if (pp < end && g == 0){
    int s0 = col[pp];
    float w = lrelu_exp(a_s[s0] + adn);
    unsigned v0 = h2u[(size_t)s0 * 32 + il];
    acc0 = fmaf(w, lof(v0), acc0);
    acc1 = fmaf(w, hif(v0), acc1);
    denom += w;
  }
  acc0 += __shfl_xor(acc0, 32);
  acc1 += __shfl_xor(acc1, 32);
  denom += __shfl_xor(denom, 32);
  float inv = 1.0f / denom;
  float2 bb = act ? *(const float2*)(b2 + il * 2) : make_float2(0.f, 0.f);
  float vv0 = act ? fmaf(acc0, inv, bb.x) : -1e30f;
  float vv1 = act ? fmaf(acc1, inv, bb.y) : -1e30f;
  float m = fmaxf(vv0, vv1);
  #pragma unroll
  for (int off = 16; off >= 1; off >>= 1) m = fmaxf(m, __shfl_xor(m, off));
  float S = act ? (__expf(vv0 - m) + __expf(vv1 - m)) : 0.f;
  #pragma unroll
  for (int off = 16; off >= 1; off >>= 1) S += __shfl_xor(S, off);
  float ls = __logf(S);
  if (tl < 20){
    float2 o = make_float2(vv0 - m - ls, vv1 - m - ls);
    *(float2*)(out + (size_t)node * 40 + il * 2) = o;
  }
}

extern "C" void kernel_launch(void* const* d_in, const int* in_sizes, int n_in,
                              void* d_out, int out_size, void* d_ws, size_t ws_size,
                              hipStream_t stream){
  const float* x    = (const float*)d_in[0];
  const int*   ei   = (const int*)d_in[1];          // int32 (jax x64 disabled)
  const float* W1   = (const float*)d_in[2];
  const float* as1w = (const float*)d_in[3];
  const float* ad1w = (const float*)d_in[4];
  const float* b1   = (const float*)d_in[5];
  const float* W2   = (const float*)d_in[6];
  const float* as2w = (const float*)d_in[7];
  const float* ad2w = (const float*)d_in[8];
  const float* b2   = (const float*)d_in[9];
  float* out = (float*)d_out;
  const int N = in_sizes[0] / 128;
  const int E = in_sizes[1] / 2;

  char* p = (char*)d_ws;
  auto alloc = [&](size_t bytes) -> void* {
    void* r = (void*)p;
    p += (bytes + 511) & ~(size_t)511;
    return r;
  };
  int*            deg      = (int*)           alloc((size_t)N * 4);
  int*            excl     = (int*)           alloc((size_t)N * 4);
  int*            partials = (int*)           alloc(64 * 4);
  int*            rank     = (int*)           alloc((size_t)E * 4);
  int*            col      = (int*)           alloc((size_t)E * 4);
  float*          a_s1     = (float*)         alloc((size_t)N * 8 * 4);
  float*          a_d1     = (float*)         alloc((size_t)N * 8 * 4);
  unsigned short* w1t      = (unsigned short*)alloc(128 * 128 * 2);
  unsigned short* out1b    = (unsigned short*)alloc((size_t)N * 128 * 2);
  unsigned short* h1b      = (unsigned short*)alloc((size_t)N * 128 * 2);
  // layer-2 temporaries overlay h1b (dead after agg1): h2b = N*64 ushorts (padded)
  unsigned short* h2b  = h1b;
  float*          a_s2 = (float*)((char*)h1b + (size_t)N * 128);  // right after padded h2b
  float*          a_d2 = a_s2 + N;

  hipMemsetAsync(deg, 0, (size_t)N * 4, stream);

  int gE8 = (E + TB * 8 - 1) / (TB * 8);
  int gE4 = (E + TB * 4 - 1) / (TB * 4);
  int nchunk = (N + SCAN_C - 1) / SCAN_C;

  k_histrank<<<gE8, TB, 0, stream>>>(ei, E, N, deg, rank);
  k_scan1   <<<nchunk, SCAN_T, 0, stream>>>(deg, N, excl, partials);
  k_scan2   <<<1, 64, 0, stream>>>(partials, nchunk);
  k_scan3   <<<(N + TB - 1) / TB, TB, 0, stream>>>(excl, N, partials);
  k_scatter <<<gE4, TB, 0, stream>>>(ei, E, N, excl, rank, col);

  k_w1t     <<<64, 256, 0, stream>>>(W1, w1t);
  k_gemm1   <<<(N + 127) / 128, 256, 0, stream>>>(x, w1t, h1b, N);
  k_att1    <<<(N * 8 + TB - 1) / TB, TB, 0, stream>>>(h1b, as1w, ad1w, a_s1, a_d1, N * 8);
  k_agg1    <<<(N + 3) / 4, 256, 0, stream>>>(h1b, a_s1, a_d1, col, excl, deg, b1, out1b, N);

  k_gemm2   <<<(N + 255) / 256, 256, 0, stream>>>(out1b, W2, h2b, N);
  k_att2    <<<(N + 31) / 32, TB, 0, stream>>>(h2b, as2w, ad2w, a_s2, a_d2, N);
  k_agg2    <<<(N + 3) / 4, 256, 0, stream>>>(h2b, a_s2, a_d2, col, excl, deg, b2, out, N);
}

// Round 10
// 372.209 us; speedup vs baseline: 1.0897x; 1.0492x over previous
//
#include <hip/hip_runtime.h>
#include <hip/hip_bf16.h>
#include <cstdint>

#define TB 256
#define SCAN_T 256
#define SCAN_C 2048

typedef __attribute__((ext_vector_type(8))) short bf16x8;
typedef __attribute__((ext_vector_type(4))) float f32x4;

__device__ __forceinline__ float lrelu_exp(float e){
  e = e > 0.0f ? e : 0.2f * e;
  return __expf(e);
}
__device__ __forceinline__ unsigned short f2bf(float f){
  unsigned u = __float_as_uint(f);
  u = (u + 0x7fffu + ((u >> 16) & 1u)) >> 16;   // RNE
  return (unsigned short)u;
}
__device__ __forceinline__ float bf2f(unsigned short s){
  return __uint_as_float(((unsigned)s) << 16);
}
__device__ __forceinline__ float lof(unsigned u){ return __uint_as_float(u << 16); }
__device__ __forceinline__ float hif(unsigned u){ return __uint_as_float(u & 0xffff0000u); }
__device__ __forceinline__ unsigned pack2(float a, float b){
  return (unsigned)f2bf(a) | ((unsigned)f2bf(b) << 16);
}

// ---------------- fused: histrank (blocks < nHist) + MFMA gemm1 ----------------
__global__ __launch_bounds__(256) void k_g1h(const float* __restrict__ x, const float* __restrict__ W1,
                                             const int* __restrict__ ei, int E, int n,
                                             int* __restrict__ deg, int* __restrict__ rank,
                                             unsigned short* __restrict__ hb, int nHist){
  if ((int)blockIdx.x < nHist){
    int b0 = blockIdx.x * (TB * 16) + threadIdx.x;
    int d[16]; int r[16]; bool ok[16];
    #pragma unroll
    for (int u = 0; u < 16; ++u){
      int e = b0 + u * TB;
      ok[u] = (e < E);
      d[u] = ok[u] ? ei[E + e] : 0;
      ok[u] = ok[u] && ((unsigned)d[u] < (unsigned)n);
    }
    #pragma unroll
    for (int u = 0; u < 16; ++u)
      if (ok[u]) r[u] = atomicAdd(&deg[d[u]], 1);
    #pragma unroll
    for (int u = 0; u < 16; ++u)
      if (ok[u]) rank[b0 + u * TB] = r[u];
    return;
  }
  // ---- gemm1: h1b[N,128](bf16) = x @ W1, MFMA 16x16x32 ----
  __shared__ __align__(16) char smem[45056];
  unsigned short (*As)[40]  = (unsigned short(*)[40])smem;            // 10240 B
  unsigned short (*Bs)[136] = (unsigned short(*)[136])(smem + 10240); // 34816 B
  unsigned short (*T)[136]  = (unsigned short(*)[136])smem;           // epilogue alias
  int t = threadIdx.x;
  int l = t & 63, wid = t >> 6;
  int wm = wid >> 1, wn = wid & 1;
  int node0 = ((int)blockIdx.x - nHist) * 128;
  {
    int k = t >> 1;
    int ch = (t & 1) * 64;
    const float4* wr = (const float4*)(W1 + (size_t)k * 128 + ch);
    #pragma unroll
    for (int u = 0; u < 16; ++u){
      float4 f = wr[u];
      int c = ch + u * 4;
      Bs[c + 0][k] = f2bf(f.x);
      Bs[c + 1][k] = f2bf(f.y);
      Bs[c + 2][k] = f2bf(f.z);
      Bs[c + 3][k] = f2bf(f.w);
    }
  }
  f32x4 acc[4][4];
  #pragma unroll
  for (int i = 0; i < 4; ++i)
    #pragma unroll
    for (int j = 0; j < 4; ++j) acc[i][j] = (f32x4){0.f, 0.f, 0.f, 0.f};

  int lrow = l & 15, lk8 = (l >> 4) * 8;
  for (int kc = 0; kc < 4; ++kc){
    __syncthreads();
    {
      int row = t >> 1, kh = t & 1;
      int gn = node0 + row;
      const float4* src = (const float4*)(x + (size_t)gn * 128 + kc * 32 + kh * 16);
      float4 z = make_float4(0.f, 0.f, 0.f, 0.f);
      float4 f0 = (gn < n) ? src[0] : z;
      float4 f1 = (gn < n) ? src[1] : z;
      float4 f2 = (gn < n) ? src[2] : z;
      float4 f3 = (gn < n) ? src[3] : z;
      uint4 p0, p1;
      p0.x = pack2(f0.x, f0.y); p0.y = pack2(f0.z, f0.w);
      p0.z = pack2(f1.x, f1.y); p0.w = pack2(f1.z, f1.w);
      p1.x = pack2(f2.x, f2.y); p1.y = pack2(f2.z, f2.w);
      p1.z = pack2(f3.x, f3.y); p1.w = pack2(f3.z, f3.w);
      *(uint4*)&As[row][kh * 16]     = p0;
      *(uint4*)&As[row][kh * 16 + 8] = p1;
    }
    __syncthreads();
    bf16x8 a[4], b[4];
    #pragma unroll
    for (int mi = 0; mi < 4; ++mi)
      a[mi] = *(const bf16x8*)&As[wm * 64 + mi * 16 + lrow][lk8];
    #pragma unroll
    for (int ni = 0; ni < 4; ++ni)
      b[ni] = *(const bf16x8*)&Bs[wn * 64 + ni * 16 + lrow][kc * 32 + lk8];
    #pragma unroll
    for (int mi = 0; mi < 4; ++mi)
      #pragma unroll
      for (int ni = 0; ni < 4; ++ni)
        acc[mi][ni] = __builtin_amdgcn_mfma_f32_16x16x32_bf16(a[mi], b[ni], acc[mi][ni], 0, 0, 0);
  }
  __syncthreads();                      // As/Bs dead; T takes over
  int rg = (l >> 4) * 4;
  #pragma unroll
  for (int mi = 0; mi < 4; ++mi)
    #pragma unroll
    for (int j = 0; j < 4; ++j){
      int nl = wm * 64 + mi * 16 + rg + j;
      #pragma unroll
      for (int ni = 0; ni < 4; ++ni)
        T[nl][wn * 64 + ni * 16 + lrow] = f2bf(acc[mi][ni][j]);
    }
  __syncthreads();
  #pragma unroll
  for (int u = 0; u < 8; ++u){
    int idx = u * 256 + t;
    int row = idx >> 4, seg = idx & 15;
    int gn = node0 + row;
    if (gn < n) *(uint4*)(hb + (size_t)gn * 128 + seg * 8) = *(const uint4*)&T[row][seg * 8];
  }
}

// ---------------- scan1: per-chunk exclusive scan + block sums ----------------
__global__ __launch_bounds__(SCAN_T) void k_scan1(const int* __restrict__ deg, int n,
                                                  int* __restrict__ excl, int* __restrict__ partials){
  __shared__ int sums[SCAN_T];
  int t = threadIdx.x;
  int base = blockIdx.x * SCAN_C + t * 8;
  int v[8]; int s = 0;
  #pragma unroll
  for (int i = 0; i < 8; ++i){ int idx = base + i; v[i] = (idx < n) ? deg[idx] : 0; s += v[i]; }
  sums[t] = s;
  __syncthreads();
  for (int off = 1; off < SCAN_T; off <<= 1){
    int add = (t >= off) ? sums[t - off] : 0;
    __syncthreads();
    sums[t] += add;
    __syncthreads();
  }
  int run = sums[t] - s;
  if (t == SCAN_T - 1) partials[blockIdx.x] = sums[t];
  #pragma unroll
  for (int i = 0; i < 8; ++i){ int idx = base + i; if (idx < n) excl[idx] = run; run += v[i]; }
}

// ---------------- scan3f: fused chunk-prefix + add ----------------
__global__ __launch_bounds__(TB) void k_scan3f(int* __restrict__ excl, int n,
                                               const int* __restrict__ partials, int nchunk){
  __shared__ int pfx[128];
  int t = threadIdx.x;
  if (t < 64){
    int carry = 0;
    for (int base = 0; base < nchunk; base += 64){
      int idx = base + t;
      int v = (idx < nchunk) ? partials[idx] : 0;
      int orig = v;
      #pragma unroll
      for (int off = 1; off < 64; off <<= 1){
        int u2 = __shfl_up(v, off);
        if (t >= off) v += u2;
      }
      if (idx < 128) pfx[idx] = carry + v - orig;
      carry += __shfl(v, 63);
    }
  }
  __syncthreads();
  int i = blockIdx.x * TB + t;
  if (i < n) excl[i] += pfx[i / SCAN_C];
}

// ---------------- fused: scatter (blocks < nScat) + att1 ----------------
__global__ __launch_bounds__(TB) void k_sa(const int* __restrict__ ei, int E, int n,
                                           const int* __restrict__ excl, const int* __restrict__ rank,
                                           int* __restrict__ col,
                                           const unsigned short* __restrict__ hb,
                                           const float* __restrict__ asw, const float* __restrict__ adw,
                                           float* __restrict__ a_s, float* __restrict__ a_d,
                                           int nScat, int n8){
  if ((int)blockIdx.x < nScat){
    int b0 = blockIdx.x * (TB * 8) + threadIdx.x;
    #pragma unroll
    for (int u = 0; u < 8; ++u){
      int e = b0 + u * TB;
      if (e >= E) continue;
      int s = ei[e];
      int d = ei[E + e];
      if ((unsigned)d >= (unsigned)n || (unsigned)s >= (unsigned)n) continue;
      int pos = excl[d] + rank[e];
      __builtin_nontemporal_store(s, &col[pos]);
    }
    return;
  }
  int idx = ((int)blockIdx.x - nScat) * TB + threadIdx.x;   // node*8 + h
  if (idx >= n8) return;
  int h = idx & 7;
  uint4 lo4 = *(const uint4*)(hb + (size_t)idx * 16);
  uint4 hi4 = *(const uint4*)(hb + (size_t)idx * 16 + 8);
  float v[16];
  unsigned w_[8] = {lo4.x, lo4.y, lo4.z, lo4.w, hi4.x, hi4.y, hi4.z, hi4.w};
  #pragma unroll
  for (int u = 0; u < 8; ++u){
    v[2 * u]     = lof(w_[u]);
    v[2 * u + 1] = hif(w_[u]);
  }
  float ss = 0.f, dd = 0.f;
  #pragma unroll
  for (int u = 0; u < 16; ++u){
    ss = fmaf(v[u], asw[h * 16 + u], ss);
    dd = fmaf(v[u], adw[h * 16 + u], dd);
  }
  a_s[idx] = ss; a_d[idx] = dd;
}

// ---------------- agg1: fused weights, 2 edge-groups of 32 lanes (uint2 = 4 ch/lane) ----------------
__global__ __launch_bounds__(256) void k_agg1(const unsigned short* __restrict__ hb, const float* __restrict__ a_s,
    const float* __restrict__ a_d, const int* __restrict__ col,
    const int* __restrict__ excl, const int* __restrict__ deg,
    const float* __restrict__ b1, unsigned short* __restrict__ out1b, int n){
  int tl = threadIdx.x & 63;
  int node = blockIdx.x * 4 + (threadIdx.x >> 6);
  if (node >= n) return;
  int g  = tl >> 5;          // edge group 0/1
  int il = tl & 31;          // channels [4il, 4il+4)
  int h  = il >> 2;
  float adn = a_d[(size_t)node * 8 + h];        // loop-invariant: dst == node
  float acc0 = 0.f, acc1 = 0.f, acc2 = 0.f, acc3 = 0.f, denom = 0.f;
  if (g == 0){
    float wSelf = lrelu_exp(a_s[(size_t)node * 8 + h] + adn);
    uint2 hv = *(const uint2*)(hb + (size_t)node * 128 + il * 4);
    acc0 = wSelf * lof(hv.x); acc1 = wSelf * hif(hv.x);
    acc2 = wSelf * lof(hv.y); acc3 = wSelf * hif(hv.y);
    denom = wSelf;
  }
  int pp = excl[node];
  int end = pp + deg[node];
  for (; pp + 16 <= end; pp += 16){
    int s[8]; float as[8]; uint2 v[8];
    #pragma unroll
    for (int u = 0; u < 8; ++u) s[u] = col[pp + 2 * u + g];
    #pragma unroll
    for (int u = 0; u < 8; ++u) as[u] = a_s[(size_t)s[u] * 8 + h];
    #pragma unroll
    for (int u = 0; u < 8; ++u) v[u] = *(const uint2*)(hb + (size_t)s[u] * 128 + il * 4);
    #pragma unroll
    for (int u = 0; u < 8; ++u){
      float w = lrelu_exp(as[u] + adn);
      acc0 = fmaf(w, lof(v[u].x), acc0);
      acc1 = fmaf(w, hif(v[u].x), acc1);
      acc2 = fmaf(w, lof(v[u].y), acc2);
      acc3 = fmaf(w, hif(v[u].y), acc3);
      denom += w;
    }
  }
  for (; pp + 2 <= end; pp += 2){
    int e = pp + g;
    int s0 = col[e];
    float w = lrelu_exp(a_s[(size_t)s0 * 8 + h] + adn);
    uint2 v0 = *(const uint2*)(hb + (size_t)s0 * 128 + il * 4);
    acc0 = fmaf(w, lof(v0.x), acc0);
    acc1 = fmaf(w, hif(v0.x), acc1);
    acc2 = fmaf(w, lof(v0.y), acc2);
    acc3 = fmaf(w, hif(v0.y), acc3);
    denom += w;
  }
  if (pp < end && g == 0){
    int s0 = col[pp];
    float w = lrelu_exp(a_s[(size_t)s0 * 8 + h] + adn);
    uint2 v0 = *(const uint2*)(hb + (size_t)s0 * 128 + il * 4);
    acc0 = fmaf(w, lof(v0.x), acc0);
    acc1 = fmaf(w, hif(v0.x), acc1);
    acc2 = fmaf(w, lof(v0.y), acc2);
    acc3 = fmaf(w, hif(v0.y), acc3);
    denom += w;
  }
  acc0 += __shfl_xor(acc0, 32); acc1 += __shfl_xor(acc1, 32);
  acc2 += __shfl_xor(acc2, 32); acc3 += __shfl_xor(acc3, 32);
  denom += __shfl_xor(denom, 32);
  float inv = 1.0f / denom;
  float4 bb = *(const float4*)(b1 + il * 4);
  float o0 = fmaf(acc0, inv, bb.x); o0 = o0 > 0.f ? o0 : 0.f;
  float o1 = fmaf(acc1, inv, bb.y); o1 = o1 > 0.f ? o1 : 0.f;
  float o2 = fmaf(acc2, inv, bb.z); o2 = o2 > 0.f ? o2 : 0.f;
  float o3 = fmaf(acc3, inv, bb.w); o3 = o3 > 0.f ? o3 : 0.f;
  if (g == 0){
    uint2 o; o.x = pack2(o0, o1); o.y = pack2(o2, o3);
    *(uint2*)(out1b + (size_t)node * 128 + il * 4) = o;
  }
}

// ---------------- gemm2 + fused att2: h2b[N,64-pad] = out1b @ W2; a_s2/a_d2 ----------------
__global__ __launch_bounds__(256) void k_gemm2a(const unsigned short* __restrict__ ab, const float* __restrict__ W2,
                                                const float* __restrict__ asw2, const float* __restrict__ adw2,
                                                unsigned short* __restrict__ h2b,
                                                float* __restrict__ a_s, float* __restrict__ a_d, int n){
  __shared__ unsigned short xs[32][256];   // 16 KB (bf16)
  __shared__ float ws[128][40];            // 20 KB
  __shared__ float ssb[256], ddb[256];     // 2 KB
  int t = threadIdx.x;
  for (int i = t; i < 128 * 40; i += 256) (&ws[0][0])[i] = W2[i];
  ssb[t] = 0.f; ddb[t] = 0.f;
  int ng = t & 63, cg = t >> 6;
  int node0 = blockIdx.x * 256;
  float acc[4][10];
  #pragma unroll
  for (int i = 0; i < 4; ++i)
    #pragma unroll
    for (int j = 0; j < 10; ++j) acc[i][j] = 0.0f;

  for (int kc = 0; kc < 4; ++kc){
    int k0 = kc * 32;
    __syncthreads();
    {
      int gn = node0 + t;
      uint4 q0, q1, r0, r1;
      uint4 z = make_uint4(0, 0, 0, 0);
      if (gn < n){
        const uint4* src = (const uint4*)(ab + (size_t)gn * 128 + k0);
        q0 = src[0]; q1 = src[1]; r0 = src[2]; r1 = src[3];
      } else { q0 = z; q1 = z; r0 = z; r1 = z; }
      unsigned w16[8] = {q0.x, q0.y, q0.z, q0.w, q1.x, q1.y, q1.z, q1.w};
      #pragma unroll
      for (int j = 0; j < 8; ++j){
        xs[j * 2][t]     = (unsigned short)(w16[j] & 0xffffu);
        xs[j * 2 + 1][t] = (unsigned short)(w16[j] >> 16);
      }
      unsigned w16b[8] = {r0.x, r0.y, r0.z, r0.w, r1.x, r1.y, r1.z, r1.w};
      #pragma unroll
      for (int j = 0; j < 8; ++j){
        xs[16 + j * 2][t]     = (unsigned short)(w16b[j] & 0xffffu);
        xs[16 + j * 2 + 1][t] = (unsigned short)(w16b[j] >> 16);
      }
    }
    __syncthreads();
    #pragma unroll 4
    for (int k = 0; k < 32; ++k){
      float xv[4];
      #pragma unroll
      for (int i = 0; i < 4; ++i) xv[i] = bf2f(xs[k][ng + 64 * i]);
      float wv[10];
      #pragma unroll
      for (int j = 0; j < 10; ++j) wv[j] = ws[k0 + k][cg * 10 + j];
      #pragma unroll
      for (int i = 0; i < 4; ++i)
        #pragma unroll
        for (int j = 0; j < 10; ++j) acc[i][j] = fmaf(xv[i], wv[j], acc[i][j]);
    }
  }
  #pragma unroll
  for (int i = 0; i < 4; ++i){
    int gn = node0 + ng + 64 * i;
    if (gn < n){
      unsigned pk[5];
      #pragma unroll
      for (int j = 0; j < 5; ++j) pk[j] = pack2(acc[i][2 * j], acc[i][2 * j + 1]);
      unsigned* dst = (unsigned*)h2b + (size_t)gn * 32 + cg * 5;   // padded stride 64 ushorts
      #pragma unroll
      for (int j = 0; j < 5; ++j) dst[j] = pk[j];
    }
  }
  // fused att2: a_s/a_d per node
  float asl[10], adl[10];
  #pragma unroll
  for (int j = 0; j < 10; ++j){ asl[j] = asw2[cg * 10 + j]; adl[j] = adw2[cg * 10 + j]; }
  #pragma unroll
  for (int i = 0; i < 4; ++i){
    float ssi = 0.f, ddi = 0.f;
    #pragma unroll
    for (int j = 0; j < 10; ++j){
      ssi = fmaf(acc[i][j], asl[j], ssi);
      ddi = fmaf(acc[i][j], adl[j], ddi);
    }
    atomicAdd(&ssb[ng + 64 * i], ssi);
    atomicAdd(&ddb[ng + 64 * i], ddi);
  }
  __syncthreads();
  int gn2 = node0 + t;
  if (gn2 < n){ a_s[gn2] = ssb[t]; a_d[gn2] = ddb[t]; }
}

// ---------------- agg2 + log_softmax: fused weights, 2 edge-groups (uint = 2 ch/lane) ----------------
__global__ __launch_bounds__(256) void k_agg2(const unsigned short* __restrict__ h2b, const float* __restrict__ a_s,
    const float* __restrict__ a_d, const int* __restrict__ col,
    const int* __restrict__ excl, const int* __restrict__ deg,
    const float* __restrict__ b2, float* __restrict__ out, int n){
  int tl = threadIdx.x & 63;
  int node = blockIdx.x * 4 + (threadIdx.x >> 6);
  if (node >= n) return;
  int g = tl >> 5, il = tl & 31;
  bool act = il < 20;                       // channels 2il, 2il+1 (< 40)
  const unsigned* h2u = (const unsigned*)h2b;   // rows of 32 uints (64 ushorts, padded)
  float adn = a_d[node];                    // loop-invariant: dst == node
  float acc0 = 0.f, acc1 = 0.f, denom = 0.f;
  if (g == 0){
    float wSelf = lrelu_exp(a_s[node] + adn);
    unsigned hv = h2u[(size_t)node * 32 + il];
    acc0 = wSelf * lof(hv); acc1 = wSelf * hif(hv);
    denom = wSelf;
  }
  int pp = excl[node];
  int end = pp + deg[node];
  for (; pp + 16 <= end; pp += 16){
    int s[8]; float as[8]; unsigned v[8];
    #pragma unroll
    for (int u = 0; u < 8; ++u) s[u] = col[pp + 2 * u + g];
    #pragma unroll
    for (int u = 0; u < 8; ++u) as[u] = a_s[s[u]];
    #pragma unroll
    for (int u = 0; u < 8; ++u) v[u] = h2u[(size_t)s[u] * 32 + il];
    #pragma unroll
    for (int u = 0; u < 8; ++u){
      float w = lrelu_exp(as[u] + adn);
      acc0 = fmaf(w, lof(v[u]), acc0);
      acc1 = fmaf(w, hif(v[u]), acc1);
      denom += w;
    }
  }
  for (; pp + 2 <= end; pp += 2){
    int e = pp + g;
    int s0 = col[e];
    float w = lrelu_exp(a_s[s0] + adn);
    unsigned v0 = h2u[(size_t)s0 * 32 + il];
    acc0 = fmaf(w, lof(v0), acc0);
    acc1 = fmaf(w, hif(v0), acc1);
    denom += w;
  }
  if (pp < end && g == 0){
    int s0 = col[pp];
    float w = lrelu_exp(a_s[s0] + adn);
    unsigned v0 = h2u[(size_t)s0 * 32 + il];
    acc0 = fmaf(w, lof(v0), acc0);
    acc1 = fmaf(w, hif(v0), acc1);
    denom += w;
  }
  acc0 += __shfl_xor(acc0, 32);
  acc1 += __shfl_xor(acc1, 32);
  denom += __shfl_xor(denom, 32);
  float inv = 1.0f / denom;
  float2 bb = act ? *(const float2*)(b2 + il * 2) : make_float2(0.f, 0.f);
  float vv0 = act ? fmaf(acc0, inv, bb.x) : -1e30f;
  float vv1 = act ? fmaf(acc1, inv, bb.y) : -1e30f;
  float m = fmaxf(vv0, vv1);
  #pragma unroll
  for (int off = 16; off >= 1; off >>= 1) m = fmaxf(m, __shfl_xor(m, off));
  float S = act ? (__expf(vv0 - m) + __expf(vv1 - m)) : 0.f;
  #pragma unroll
  for (int off = 16; off >= 1; off >>= 1) S += __shfl_xor(S, off);
  float ls = __logf(S);
  if (tl < 20){
    float2 o = make_float2(vv0 - m - ls, vv1 - m - ls);
    *(float2*)(out + (size_t)node * 40 + il * 2) = o;
  }
}

extern "C" void kernel_launch(void* const* d_in, const int* in_sizes, int n_in,
                              void* d_out, int out_size, void* d_ws, size_t ws_size,
                              hipStream_t stream){
  const float* x    = (const float*)d_in[0];
  const int*   ei   = (const int*)d_in[1];          // int32 (jax x64 disabled)
  const float* W1   = (const float*)d_in[2];
  const float* as1w = (const float*)d_in[3];
  const float* ad1w = (const float*)d_in[4];
  const float* b1   = (const float*)d_in[5];
  const float* W2   = (const float*)d_in[6];
  const float* as2w = (const float*)d_in[7];
  const float* ad2w = (const float*)d_in[8];
  const float* b2   = (const float*)d_in[9];
  float* out = (float*)d_out;
  const int N = in_sizes[0] / 128;
  const int E = in_sizes[1] / 2;

  char* p = (char*)d_ws;
  auto alloc = [&](size_t bytes) -> void* {
    void* r = (void*)p;
    p += (bytes + 511) & ~(size_t)511;
    return r;
  };
  int*            deg      = (int*)           alloc((size_t)N * 4);
  int*            excl     = (int*)           alloc((size_t)N * 4);
  int*            partials = (int*)           alloc(128 * 4);
  int*            rank     = (int*)           alloc((size_t)E * 4);
  int*            col      = (int*)           alloc((size_t)E * 4);
  float*          a_s1     = (float*)         alloc((size_t)N * 8 * 4);
  float*          a_d1     = (float*)         alloc((size_t)N * 8 * 4);
  unsigned short* out1b    = (unsigned short*)alloc((size_t)N * 128 * 2);
  unsigned short* h1b      = (unsigned short*)alloc((size_t)N * 128 * 2);
  // layer-2 temporaries overlay h1b (dead after agg1): h2b = N*64 ushorts (padded)
  unsigned short* h2b  = h1b;
  float*          a_s2 = (float*)((char*)h1b + (size_t)N * 128);  // right after padded h2b
  float*          a_d2 = a_s2 + N;

  hipMemsetAsync(deg, 0, (size_t)N * 4, stream);

  int nHist  = (E + TB * 16 - 1) / (TB * 16);
  int nG1    = (N + 127) / 128;
  int nScat  = (E + TB * 8 - 1) / (TB * 8);
  int nA1    = (N * 8 + TB - 1) / TB;
  int nchunk = (N + SCAN_C - 1) / SCAN_C;

  k_g1h    <<<nHist + nG1, 256, 0, stream>>>(x, W1, ei, E, N, deg, rank, h1b, nHist);
  k_scan1  <<<nchunk, SCAN_T, 0, stream>>>(deg, N, excl, partials);
  k_scan3f <<<(N + TB - 1) / TB, TB, 0, stream>>>(excl, N, partials, nchunk);
  k_sa     <<<nScat + nA1, TB, 0, stream>>>(ei, E, N, excl, rank, col, h1b, as1w, ad1w, a_s1, a_d1, nScat, N * 8);
  k_agg1   <<<(N + 3) / 4, 256, 0, stream>>>(h1b, a_s1, a_d1, col, excl, deg, b1, out1b, N);
  k_gemm2a <<<(N + 255) / 256, 256, 0, stream>>>(out1b, W2, as2w, ad2w, h2b, a_s2, a_d2, N);
  k_agg2   <<<(N + 3) / 4, 256, 0, stream>>>(h2b, a_s2, a_d2, col, excl, deg, b2, out, N);
}